// Round 8
// baseline (277.432 us; speedup 1.0000x reference)
//
#include <hip/hip_runtime.h>
#include <hip/hip_bf16.h>
#include <math.h>

#define N_HEADS 12
#define L_SEQ   2048
#define BATCH   2
#define D_KQ    192
#define D_OUT   1152
#define D_KV    1344   // 192 + 1152
#define D_KVQ   1536   // 192 + 1152 + 192 (fused q columns)
#define D_X     768
#define D_SIDE  384
#define HD_K    16
#define HD_V    96
#define M_ROWS  4096

typedef __attribute__((ext_vector_type(8))) short bf16x8;
typedef __attribute__((ext_vector_type(4))) float f32x4;

__device__ inline ushort f2b(float f){ __hip_bfloat16 h = __float2bfloat16(f);
                                       return *reinterpret_cast<ushort*>(&h); }

__device__ inline void gload_lds16(const ushort* g, ushort* l) {
    __builtin_amdgcn_global_load_lds(
        (const __attribute__((address_space(1))) void*)g,
        (__attribute__((address_space(3))) void*)l, 16, 0, 0);
}

// swizzled ushort index for [R][64] bf16 LDS tiles (XOR elem bits 3..5 = byte
// bits 4..6 with row&7). Same involution applied to the staging source address.
#define SWZ(r, c) ((((r) * 64) + (c)) ^ (((r) & 7) << 3))

// ---------------------------------------------------------------------------
// Input prep: xs_bf[4096][1152] = bf16(concat(x, side)) in one launch.
// ---------------------------------------------------------------------------
__global__ __launch_bounds__(256)
void cvt_inputs(const float* __restrict__ x, const float* __restrict__ side,
                ushort* __restrict__ xs_bf) {
    const int gid = blockIdx.x * 256 + threadIdx.x;
    if (gid < 786432) {                       // x part: 192 float4 per row
        const int r = gid / 192, c = (gid - r * 192) * 4;
        float4 v = *reinterpret_cast<const float4*>(&x[(size_t)r * D_X + c]);
        ushort4 o = make_ushort4(f2b(v.x), f2b(v.y), f2b(v.z), f2b(v.w));
        *reinterpret_cast<ushort4*>(&xs_bf[(size_t)r * D_OUT + c]) = o;
    } else {                                  // side part: 96 float4 per row
        const int g2 = gid - 786432;
        const int r = g2 / 96, c = (g2 - r * 96) * 4;
        float4 v = *reinterpret_cast<const float4*>(&side[(size_t)r * D_SIDE + c]);
        ushort4 o = make_ushort4(f2b(v.x), f2b(v.y), f2b(v.z), f2b(v.w));
        *reinterpret_cast<ushort4*>(&xs_bf[(size_t)r * D_OUT + D_X + c]) = o;
    }
}

// ---------------------------------------------------------------------------
// Fused kvq weight transpose: virtual W2[1152][1536] = [Wkv | [0;Wq]]
//   -> wt[1536][1152] bf16.  Grid (48, 36).
// ---------------------------------------------------------------------------
__global__ __launch_bounds__(256)
void transpose_kvq(const float* __restrict__ Wkv, const float* __restrict__ Wq,
                   ushort* __restrict__ Wt) {
    __shared__ float t[32][33];
    const int n0 = blockIdx.x * 32, k0 = blockIdx.y * 32;
    const int tx = threadIdx.x & 31, ty = threadIdx.x >> 5;   // ty 0..7
#pragma unroll
    for (int i = 0; i < 4; i++) {
        const int k = k0 + ty + i * 8, n = n0 + tx;
        float v;
        if (n < D_KV)        v = Wkv[(size_t)k * D_KV + n];
        else if (k >= D_X)   v = Wq[(size_t)(k - D_X) * D_KQ + (n - D_KV)];
        else                 v = 0.f;
        t[ty + i * 8][tx] = v;
    }
    __syncthreads();
#pragma unroll
    for (int i = 0; i < 4; i++) {
        const int n = n0 + ty + i * 8;
        Wt[(size_t)n * D_OUT + k0 + tx] = f2b(t[tx][ty + i * 8]);
    }
}

// ---------------------------------------------------------------------------
// W[K][N] f32 -> Wt[N][K] bf16 (square, in-bounds). Grid (N/32, K/32).
// ---------------------------------------------------------------------------
__global__ __launch_bounds__(256)
void transpose_cvt(const float* __restrict__ W, ushort* __restrict__ Wt,
                   int K, int N) {
    __shared__ float t[32][33];
    const int n0 = blockIdx.x * 32, k0 = blockIdx.y * 32;
    const int tx = threadIdx.x & 31, ty = threadIdx.x >> 5;
#pragma unroll
    for (int i = 0; i < 4; i++)
        t[ty + i * 8][tx] = W[(size_t)(k0 + ty + i * 8) * N + n0 + tx];
    __syncthreads();
#pragma unroll
    for (int i = 0; i < 4; i++) {
        const int n = n0 + ty + i * 8;
        Wt[(size_t)n * K + k0 + tx] = f2b(t[tx][ty + i * 8]);
    }
}

// ---------------------------------------------------------------------------
// bf16 MFMA GEMM: C[M,N] = A[M,K] @ Wt[N,K]^T + bias.  128x128 tile, BK=32,
// 4 waves x (64x64), 16x16x32 MFMA, global_load_lds(16) staging.
// Software-pipelined: LDS double-buffer, stage k+1 before compute k,
// counted s_waitcnt vmcnt(4) + raw barriers (never drain mid-loop).
// MODE 0: f32 C.  MODE 2: fused kvq epilogue —
//   col<192: K -> Cv[row][192] bf16;  192..1343: V -> vt[b][h][d][row];
//   >=1344: Q -> qout[row][192] bf16 (bias from bias2).
// ---------------------------------------------------------------------------
template<int MODE>
__global__ __launch_bounds__(256)
void gemm_mfma(const ushort* __restrict__ A, const ushort* __restrict__ Bt,
               const float* __restrict__ bias, const float* __restrict__ bias2,
               void* __restrict__ Cv, ushort* __restrict__ vt,
               ushort* __restrict__ qout, int M, int N, int K) {
    __shared__ __align__(16) ushort As[2][128 * 32];
    __shared__ __align__(16) ushort Bs[2][128 * 32];
    const int tid = threadIdx.x;
    const int w = tid >> 6, lane = tid & 63;
    const int wr = w >> 1, wc = w & 1;
    const int n0 = blockIdx.x * 128, m0 = blockIdx.y * 128;
    const int l4 = lane & 3, lrow = lane >> 2;
    const int kgrp = lane >> 4, l16 = lane & 15;

    f32x4 acc[4][4];
#pragma unroll
    for (int i = 0; i < 4; i++)
#pragma unroll
        for (int j = 0; j < 4; j++)
            acc[i][j] = (f32x4){0.f, 0.f, 0.f, 0.f};

    auto stage = [&](int buf, int kt) {
#pragma unroll
        for (int r = 0; r < 2; r++) {
            const int seg = r * 4 + w;              // 0..7, wave-uniform
            const int trow = seg * 16 + lrow;
            gload_lds16(&A [(size_t)(m0 + trow) * K + kt * 32 + l4 * 8],
                        &As[buf][seg * 512]);
            gload_lds16(&Bt[(size_t)(n0 + trow) * K + kt * 32 + l4 * 8],
                        &Bs[buf][seg * 512]);
        }
    };

    const int KT = K >> 5;
    stage(0, 0);
    int cur = 0;
    for (int kt = 0; kt < KT; ++kt) {
        if (kt + 1 < KT) {
            stage(cur ^ 1, kt + 1);                 // 4 newest loads in flight
            asm volatile("s_waitcnt vmcnt(4)" ::: "memory");
        } else {
            asm volatile("s_waitcnt vmcnt(0)" ::: "memory");
        }
        __builtin_amdgcn_s_barrier();               // everyone's buf[cur] ready
        __builtin_amdgcn_sched_barrier(0);

        bf16x8 a[4], b[4];
#pragma unroll
        for (int i = 0; i < 4; i++)
            a[i] = *reinterpret_cast<const bf16x8*>(
                &As[cur][(wr * 64 + i * 16 + l16) * 32 + kgrp * 8]);
#pragma unroll
        for (int j = 0; j < 4; j++)
            b[j] = *reinterpret_cast<const bf16x8*>(
                &Bs[cur][(wc * 64 + j * 16 + l16) * 32 + kgrp * 8]);
        __builtin_amdgcn_s_setprio(1);
#pragma unroll
        for (int i = 0; i < 4; i++)
#pragma unroll
            for (int j = 0; j < 4; j++)
                acc[i][j] = __builtin_amdgcn_mfma_f32_16x16x32_bf16(
                    a[i], b[j], acc[i][j], 0, 0, 0);
        __builtin_amdgcn_s_setprio(0);

        __builtin_amdgcn_s_barrier();               // reads done before overwrite
        __builtin_amdgcn_sched_barrier(0);
        cur ^= 1;
    }

    const int rgrp = lane >> 4;
#pragma unroll
    for (int j = 0; j < 4; j++) {
        const int col = n0 + wc * 64 + j * 16 + l16;
        if constexpr (MODE == 2) {
            if (col < D_KQ) {                       // K column
                const float bv = bias[col];
#pragma unroll
                for (int i = 0; i < 4; i++) {
                    const int row0 = m0 + wr * 64 + i * 16 + rgrp * 4;
#pragma unroll
                    for (int rg = 0; rg < 4; rg++)
                        ((ushort*)Cv)[(size_t)(row0 + rg) * D_KQ + col] =
                            f2b(acc[i][j][rg] + bv);
                }
            } else if (col < D_KV) {                // V column -> transposed
                const float bv = bias[col];
                const int hh = (col - D_KQ) / HD_V;
                const int dd = (col - D_KQ) % HD_V;
                const int bb = m0 >> 11;
                ushort* vrow = vt + ((size_t)(bb * N_HEADS + hh) * HD_V + dd) * L_SEQ
                                  + (m0 & 2047);
#pragma unroll
                for (int i = 0; i < 4; i++) {
                    const int r0 = wr * 64 + i * 16 + rgrp * 4;
                    ushort4 o = make_ushort4(
                        f2b(acc[i][j][0] + bv), f2b(acc[i][j][1] + bv),
                        f2b(acc[i][j][2] + bv), f2b(acc[i][j][3] + bv));
                    *reinterpret_cast<ushort4*>(&vrow[r0]) = o;
                }
            } else {                                // Q column
                const int qc = col - D_KV;
                const float bv = bias2[qc];
#pragma unroll
                for (int i = 0; i < 4; i++) {
                    const int row0 = m0 + wr * 64 + i * 16 + rgrp * 4;
#pragma unroll
                    for (int rg = 0; rg < 4; rg++)
                        qout[(size_t)(row0 + rg) * D_KQ + qc] =
                            f2b(acc[i][j][rg] + bv);
                }
            }
            continue;
        }
        if (col >= N) continue;
        const float bv = bias[col];
#pragma unroll
        for (int i = 0; i < 4; i++) {
            const int row0 = m0 + wr * 64 + i * 16 + rgrp * 4;
#pragma unroll
            for (int rg = 0; rg < 4; rg++)
                ((float*)Cv)[(size_t)(row0 + rg) * N + col] = acc[i][j][rg] + bv;
        }
    }
}

// ---------------------------------------------------------------------------
// MFMA flash attention, software-pipelined. One block = 32 q-rows x 1 head;
// 2 waves, wave w owns q-rows [w*16, w*16+16). Grid 1536, CU-pair balance.
// Per tile: K[cur] prefetched 1 tile ahead (dbuf); V staged after QK so its
// HBM latency hides under softmax; counted vmcnt waits + raw barriers.
// Seq row 0 produces NaN (l=0); first_kernel overwrites it afterwards.
// ---------------------------------------------------------------------------
__global__ __launch_bounds__(128)
void attn_mfma(const ushort* __restrict__ qbuf, const ushort* __restrict__ kb,
               const ushort* __restrict__ vtg, ushort* __restrict__ yb) {
    __shared__ __align__(16) ushort Vt[96 * 64];     // 12 KB swizzled [dim][key]
    __shared__ __align__(16) ushort Ks[2][1024];     //  4 KB dbuf [key][16]
    __shared__ __align__(16) ushort Ps[2][16 * 64];  //  4 KB per-wave P, swizzled

    const int tid = threadIdx.x;
    const int w = tid >> 6, lane = tid & 63;
    const int l16 = lane & 15, kgrp = lane >> 4;

    // balanced mapping: i -> (t, hb); blocks c, c+256, ... alternate t / 63-t
    const int i = blockIdx.x, j5 = i & 255, g = i >> 8;         // g 0..5
    const int tb = j5 & 63;
    const int t  = (g & 1) ? (63 - tb) : tb;                    // q-tile 0..63
    const int hb = (g << 2) | (j5 >> 6);                        // 0..23
    const int h = hb % N_HEADS, b = hb / N_HEADS;

    const ushort* vt_h  = vtg + (size_t)(b * N_HEADS + h) * HD_V * L_SEQ;
    const ushort* kbase = kb + (size_t)b * L_SEQ * D_KQ;
    const int rowbase = t * 32;
    const int nt = (t >> 1) + 1;            // 64-key tiles needed
    const int rowoff = (t & 1) * 32;        // diag-tile row offset

    // per-lane staging offsets (inverse-swizzled global source)
    int voff[6];
#pragma unroll
    for (int s6 = 0; s6 < 6; s6++) {
        const int L = (w * 6 + s6) * 1024 + lane * 16;     // LDS byte
        const int X = L ^ (((L >> 7) & 7) << 4);           // logical byte
        voff[s6] = (X >> 7) * L_SEQ + ((X >> 1) & 63);     // dim*2048 + key
    }
    int koff;
    {
        const int elem = (w * 1024 + lane * 16) >> 1;
        koff = (elem >> 4) * D_KQ + h * HD_K + ((elem >> 3) & 1) * 8;
    }

    // Q fragment (constant across tiles)
    bf16x8 qf = {0, 0, 0, 0, 0, 0, 0, 0};
    if (kgrp < 2)
        qf = *reinterpret_cast<const bf16x8*>(
            qbuf + ((size_t)b * L_SEQ + rowbase + w * 16 + l16) * D_KQ
                 + h * HD_K + kgrp * 8);

    float m[4] = {-INFINITY, -INFINITY, -INFINITY, -INFINITY};
    float l[4] = {0.f, 0.f, 0.f, 0.f};
    f32x4 acc[6];
#pragma unroll
    for (int ob = 0; ob < 6; ob++) acc[ob] = (f32x4){0.f, 0.f, 0.f, 0.f};

    // prologue: stage K tile 0
    gload_lds16(kbase + koff, &Ks[0][w * 512]);
    int cur = 0;

    for (int t2 = 0; t2 < nt; t2++) {
        const int j0 = t2 * 64;
        const bool diag = (t2 == nt - 1);

        // own K[cur] landed (only pending vmem op at this point)
        asm volatile("s_waitcnt vmcnt(0) lgkmcnt(0)" ::: "memory");
        __builtin_amdgcn_s_barrier();              // B1: K ready; prev Vt reads done
        __builtin_amdgcn_sched_barrier(0);

        // ---- QK^T: 4 mfma from Ks[cur] ----
        __builtin_amdgcn_s_setprio(1);
        f32x4 s[4];
#pragma unroll
        for (int f = 0; f < 4; f++) {
            bf16x8 kf = {0, 0, 0, 0, 0, 0, 0, 0};
            if (kgrp < 2)
                kf = *reinterpret_cast<const bf16x8*>(
                    &Ks[cur][(f * 16 + l16) * 16 + kgrp * 8]);
            s[f] = __builtin_amdgcn_mfma_f32_16x16x32_bf16(
                qf, kf, (f32x4){0.f, 0.f, 0.f, 0.f}, 0, 0, 0);
        }
        __builtin_amdgcn_s_setprio(0);

        // ---- stage V (this tile) + K (next tile, other buffer) ----
#pragma unroll
        for (int s6 = 0; s6 < 6; s6++)
            gload_lds16(vt_h + voff[s6] + j0, &Vt[(w * 6 + s6) * 512]);
        if (t2 + 1 < nt)
            gload_lds16(kbase + (size_t)(j0 + 64) * D_KQ + koff,
                        &Ks[cur ^ 1][w * 512]);

        // ---- scale + causal mask (key_abs < row_abs) ----
#pragma unroll
        for (int f = 0; f < 4; f++)
#pragma unroll
            for (int r = 0; r < 4; r++) {
                float v = s[f][r] * 0.25f;
                if (diag) {
                    const int row32 = w * 16 + kgrp * 4 + r;
                    const int key64 = f * 16 + l16;
                    if (key64 >= rowoff + row32) v = -INFINITY;
                }
                s[f][r] = v;
            }

        // ---- online softmax per reg-row r ----
        float scl[4];
#pragma unroll
        for (int r = 0; r < 4; r++) {
            float mt = fmaxf(fmaxf(s[0][r], s[1][r]), fmaxf(s[2][r], s[3][r]));
            mt = fmaxf(mt, __shfl_xor(mt, 1));
            mt = fmaxf(mt, __shfl_xor(mt, 2));
            mt = fmaxf(mt, __shfl_xor(mt, 4));
            mt = fmaxf(mt, __shfl_xor(mt, 8));
            const float mn = fmaxf(m[r], mt);
            scl[r] = __expf(m[r] - mn);     // NaN only for seq row 0
            m[r] = mn;
            float ps = 0.f;
#pragma unroll
            for (int f = 0; f < 4; f++) {
                float p = __expf(s[f][r] - mn);
                s[f][r] = p;
                ps += p;
            }
            ps += __shfl_xor(ps, 1);
            ps += __shfl_xor(ps, 2);
            ps += __shfl_xor(ps, 4);
            ps += __shfl_xor(ps, 8);
            l[r] = l[r] * scl[r] + ps;
        }

        // ---- P -> bf16 -> per-wave LDS; rescale O ----
#pragma unroll
        for (int f = 0; f < 4; f++)
#pragma unroll
            for (int r = 0; r < 4; r++)
                Ps[w][SWZ(kgrp * 4 + r, f * 16 + l16)] = f2b(s[f][r]);
#pragma unroll
        for (int ob = 0; ob < 6; ob++)
#pragma unroll
            for (int r = 0; r < 4; r++)
                acc[ob][r] *= scl[r];

        // wait own V (K-next is the single newest op); drain own Ps writes
        if (t2 + 1 < nt)
            asm volatile("s_waitcnt vmcnt(1) lgkmcnt(0)" ::: "memory");
        else
            asm volatile("s_waitcnt vmcnt(0) lgkmcnt(0)" ::: "memory");
        __builtin_amdgcn_sched_barrier(0);
        __builtin_amdgcn_s_barrier();              // B2: all V staged, P ready
        __builtin_amdgcn_sched_barrier(0);

        // ---- PV: 12 mfma ----
        bf16x8 pa0 = *reinterpret_cast<const bf16x8*>(&Ps[w][SWZ(l16, kgrp * 8)]);
        bf16x8 pa1 = *reinterpret_cast<const bf16x8*>(&Ps[w][SWZ(l16, 32 + kgrp * 8)]);
        __builtin_amdgcn_s_setprio(1);
#pragma unroll
        for (int ob = 0; ob < 6; ob++) {
            bf16x8 vb0 = *reinterpret_cast<const bf16x8*>(&Vt[SWZ(ob * 16 + l16, kgrp * 8)]);
            bf16x8 vb1 = *reinterpret_cast<const bf16x8*>(&Vt[SWZ(ob * 16 + l16, 32 + kgrp * 8)]);
            acc[ob] = __builtin_amdgcn_mfma_f32_16x16x32_bf16(pa0, vb0, acc[ob], 0, 0, 0);
            acc[ob] = __builtin_amdgcn_mfma_f32_16x16x32_bf16(pa1, vb1, acc[ob], 0, 0, 0);
        }
        __builtin_amdgcn_s_setprio(0);
        cur ^= 1;
    }

    // ---- epilogue: divide by l, write bf16 ----
#pragma unroll
    for (int r = 0; r < 4; r++) {
        const float inv = 1.f / l[r];
        ushort* dst = yb + ((size_t)b * L_SEQ + rowbase + w * 16 + kgrp * 4 + r) * D_OUT
                        + h * HD_V;
#pragma unroll
        for (int ob = 0; ob < 6; ob++)
            dst[ob * 16 + l16] = f2b(acc[ob][r] * inv);
    }
}

// ---------------------------------------------------------------------------
// first = side[:,0] @ Wemb + bemb  -> y[:, 0, :]  (bf16)
// ---------------------------------------------------------------------------
__global__ __launch_bounds__(128)
void first_kernel(const float* __restrict__ side, const float* __restrict__ Wemb,
                  const float* __restrict__ bemb, ushort* __restrict__ yb) {
    const int o = blockIdx.x * 128 + threadIdx.x;   // 0..1151
    const int b = blockIdx.y;
    const float* s = side + (size_t)b * L_SEQ * D_SIDE;
    float acc = bemb[o];
    for (int k = 0; k < D_SIDE; k++)
        acc += s[k] * Wemb[(size_t)k * D_OUT + o];
    yb[(size_t)b * L_SEQ * D_OUT + o] = f2b(acc);
}

// ---------------------------------------------------------------------------
extern "C" void kernel_launch(void* const* d_in, const int* in_sizes, int n_in,
                              void* d_out, int out_size, void* d_ws, size_t ws_size,
                              hipStream_t stream) {
    const float* x     = (const float*)d_in[0];
    const float* side  = (const float*)d_in[1];
    const float* Wq    = (const float*)d_in[2];
    const float* bq    = (const float*)d_in[3];
    const float* Wkv   = (const float*)d_in[4];
    const float* bkv   = (const float*)d_in[5];
    const float* Wproj = (const float*)d_in[6];
    const float* bproj = (const float*)d_in[7];
    const float* Wemb  = (const float*)d_in[8];
    const float* bemb  = (const float*)d_in[9];
    float* out = (float*)d_out;

    char* ws = (char*)d_ws;
    ushort* xs_bf   = (ushort*)(ws + 0);          // [4096][1152]  9437184 B
    ushort* wkvq_t  = (ushort*)(ws + 9437184);    // [1536][1152]  3538944 B
    ushort* wproj_t = (ushort*)(ws + 12976128);   // [1152][1152]  2654208 B
    ushort* qbuf    = (ushort*)(ws + 15630336);   // [4096][192]   1572864 B
    ushort* kbuf    = (ushort*)(ws + 17203200);   // [4096][192]   1572864 B
    ushort* vtg     = (ushort*)(ws + 18776064);   // [24][96][2048] 9437184 B
    ushort* ybuf    = (ushort*)(ws + 28213248);   // [4096][1152]  9437184 B

    // prep: bf16 concat + weight transposes (3 launches)
    cvt_inputs<<<4608, 256, 0, stream>>>(x, side, xs_bf);
    transpose_kvq<<<dim3(48, 36), 256, 0, stream>>>(Wkv, Wq, wkvq_t);
    transpose_cvt<<<dim3(36, 36), 256, 0, stream>>>(Wproj, wproj_t, D_OUT, D_OUT);

    // fused kvq GEMM: [x,side]@[Wkv | 0;Wq] -> kbuf, vtg (transposed), qbuf
    gemm_mfma<2><<<dim3(12, 32), 256, 0, stream>>>(
        xs_bf, wkvq_t, bkv, bq, kbuf, vtg, qbuf, M_ROWS, D_KVQ, D_OUT);

    // attention (MFMA flash, pipelined) -> ybuf bf16
    attn_mfma<<<1536, 128, 0, stream>>>(qbuf, kbuf, vtg, ybuf);

    // first-token override (row 0 of each batch) -- after attn
    first_kernel<<<dim3(9, BATCH), 128, 0, stream>>>(side, Wemb, bemb, ybuf);

    // out = y @ Wproj + bproj -> f32
    gemm_mfma<0><<<dim3(9, 32), 256, 0, stream>>>(
        ybuf, wproj_t, bproj, nullptr, out, nullptr, nullptr, M_ROWS, D_OUT, D_OUT);
}